// Round 1
// baseline (870.979 us; speedup 1.0000x reference)
//
#include <hip/hip_runtime.h>
#include <cstdint>
#include <cstddef>

#define N_SENT 65536
#define DIMS   2304
#define NBAG   4096
#define NCLS   53
#define CPAD   64
#define PROW   56   // probs row stride in floats (16B aligned)

// ---------------- ws layout (bytes) ----------------
// Wt    : [DIMS][CPAD] float   @ 0          (589824 B)
// probs : [N_SENT][PROW] float @ 589824     (14680064 B)
// lp    : [N_SENT] float       @ 15269888   (262144 B)
// tcls  : [N_SENT] int         @ 15532032   (262144 B)

__device__ __forceinline__ void async_copy16(const float* g, float* l) {
    __builtin_amdgcn_global_load_lds(
        (const __attribute__((address_space(1))) unsigned int*)g,
        (__attribute__((address_space(3))) unsigned int*)l,
        16, 0, 0);
}

// ------------- kernel 0: transpose W (pad classes to 64), fill tcls -------------
__global__ void prep_kernel(const float* __restrict__ W,
                            const int* __restrict__ scope,
                            const int* __restrict__ label,
                            float* __restrict__ Wt,
                            int* __restrict__ tcls) {
    int gid = blockIdx.x * 256 + threadIdx.x;
    if (blockIdx.x < (DIMS * CPAD) / 256) {          // 576 blocks
        int k = gid >> 6;
        int c = gid & 63;
        Wt[gid] = (c < NCLS) ? W[(size_t)c * DIMS + k] : 0.0f;
    } else {
        int bag = gid - (DIMS * CPAD);
        if (bag < NBAG) {
            int s = scope[bag], e = scope[bag + 1];
            int lb = label[bag];
            for (int j = s; j < e; ++j) tcls[j] = lb;
        }
    }
}

// ------------- kernel 1: logits -> softmax -> probs + lp -------------
// grid 512, block 256. Tile: 128 sentences x 64 classes, K chunks of 64.
// thread (ct = tid&15, mt = tid>>4) owns sentences {mt+16i, i<8} x classes {4ct..4ct+3}.
__launch_bounds__(256, 2)
__global__ void logits_kernel(const float* __restrict__ reps,
                              const float* __restrict__ Wt,
                              const float* __restrict__ bias_g,
                              const int* __restrict__ tcls,
                              float* __restrict__ probs,
                              float* __restrict__ lp) {
    __shared__ float sA[128 * 64];   // reps tile, rows rotated by 4*(m&15) chunks
    __shared__ float sW[64 * CPAD];  // Wt chunk [k][64 classes]

    const int tid  = threadIdx.x;
    const int ct   = tid & 15;
    const int mt   = tid >> 4;
    const int wave = tid >> 6;
    const int lane = tid & 63;
    const int m0   = blockIdx.x * 128;

    float acc[8][4];
#pragma unroll
    for (int i = 0; i < 8; ++i)
#pragma unroll
        for (int c = 0; c < 4; ++c) acc[i][c] = 0.0f;

    const int r_in = lane >> 4;   // row within one 1KB staging instr (0..3)
    const int jj   = lane & 15;   // 16B chunk within row

    for (int kc = 0; kc < DIMS; kc += 64) {
        // ---- stage reps tile: 8 wave-instrs/wave, lane fetches the rotated chunk ----
#pragma unroll
        for (int s = 0; s < 8; ++s) {
            int r  = (wave * 8 + s) * 4 + r_in;                   // tile row 0..127
            int gk = kc + (((jj - (r & 15)) * 4) & 63);           // rotation by 4*(m&15)
            const float* gptr = reps + (size_t)(m0 + r) * DIMS + gk;
            float* lptr = sA + (wave * 8 + s) * 256;              // wave-uniform base
            async_copy16(gptr, lptr);
        }
        // ---- stage Wt chunk: straight contiguous copy, 4 wave-instrs/wave ----
#pragma unroll
        for (int s = 0; s < 4; ++s) {
            const float* gptr = Wt + (size_t)kc * CPAD + (wave * 4 + s) * 256 + lane * 4;
            float* lptr = sW + (wave * 4 + s) * 256;
            async_copy16(gptr, lptr);
        }
        __syncthreads();

        // ---- inner product: per 4 k-steps: 12 ds_read_b128 + 128 v_fma_f32 ----
        for (int kk = 0; kk < 64; kk += 4) {
            float4 wv[4];
#pragma unroll
            for (int j = 0; j < 4; ++j)
                wv[j] = *(const float4*)&sW[(kk + j) * CPAD + 4 * ct];
            const int col = (kk + 4 * mt) & 63;
#pragma unroll
            for (int i = 0; i < 8; ++i) {
                float4 rv = *(const float4*)&sA[(mt + 16 * i) * 64 + col];
                const float rk[4] = {rv.x, rv.y, rv.z, rv.w};
#pragma unroll
                for (int j = 0; j < 4; ++j) {
                    const float* wj = (const float*)&wv[j];
#pragma unroll
                    for (int c = 0; c < 4; ++c)
                        acc[i][c] = fmaf(rk[j], wj[c], acc[i][c]);
                }
            }
        }
        __syncthreads();
    }

    // ---- epilogue: bias + softmax over 53 classes (16-lane butterfly) ----
    float bv[4];
    bool  valid[4];
#pragma unroll
    for (int c = 0; c < 4; ++c) {
        int cc = 4 * ct + c;
        valid[c] = (cc < NCLS);
        bv[c] = valid[c] ? bias_g[cc] : 0.0f;
    }

#pragma unroll
    for (int i = 0; i < 8; ++i) {
        int m = m0 + mt + 16 * i;
        float l[4];
        float mx = -1e30f;
#pragma unroll
        for (int c = 0; c < 4; ++c) {
            l[c] = valid[c] ? (acc[i][c] + bv[c]) : -1e30f;
            mx = fmaxf(mx, l[c]);
        }
#pragma unroll
        for (int off = 1; off < 16; off <<= 1)
            mx = fmaxf(mx, __shfl_xor(mx, off, 16));
        float e[4];
        float s = 0.0f;
#pragma unroll
        for (int c = 0; c < 4; ++c) {
            e[c] = valid[c] ? __expf(l[c] - mx) : 0.0f;
            s += e[c];
        }
#pragma unroll
        for (int off = 1; off < 16; off <<= 1)
            s += __shfl_xor(s, off, 16);
        float inv = 1.0f / s;

        float4 pv = make_float4(e[0] * inv, e[1] * inv, e[2] * inv, e[3] * inv);
        float* prow = probs + (size_t)m * PROW;
        if (ct < 13)       *(float4*)(prow + 4 * ct) = pv;
        else if (ct == 13) prow[52] = pv.x;

        int t = tcls[m];
        if ((t >> 2) == ct) {
            const float* pe = (const float*)&pv;
            lp[m] = pe[t & 3];
        }
    }
}

// ------------- kernel 2: per-bag first-argmax over lp, gather probs row -------------
__global__ void select_kernel(const int* __restrict__ scope,
                              const float* __restrict__ lp,
                              const float* __restrict__ probs,
                              float* __restrict__ out) {
    int wave = threadIdx.x >> 6;
    int lane = threadIdx.x & 63;
    int bag  = blockIdx.x * 4 + wave;
    int s = scope[bag], e = scope[bag + 1];

    float bvv = -1e38f;
    int   bj  = 0x7fffffff;
    for (int j = s + lane; j < e; j += 64) {
        float v = lp[j];
        if (v > bvv) { bvv = v; bj = j; }   // strict > keeps first max per lane
    }
#pragma unroll
    for (int off = 1; off < 64; off <<= 1) {
        float ov = __shfl_xor(bvv, off, 64);
        int   oj = __shfl_xor(bj, off, 64);
        if (ov > bvv || (ov == bvv && oj < bj)) { bvv = ov; bj = oj; }
    }
    if (lane < NCLS)
        out[(size_t)bag * NCLS + lane] = probs[(size_t)bj * PROW + lane];
}

extern "C" void kernel_launch(void* const* d_in, const int* in_sizes, int n_in,
                              void* d_out, int out_size, void* d_ws, size_t ws_size,
                              hipStream_t stream) {
    const float* reps  = (const float*)d_in[0];
    const int*   scope = (const int*)d_in[1];
    const int*   label = (const int*)d_in[2];
    const float* W     = (const float*)d_in[3];
    const float* b     = (const float*)d_in[4];
    float*       out   = (float*)d_out;

    char* ws = (char*)d_ws;
    float* Wt    = (float*)(ws);
    float* probs = (float*)(ws + 589824);
    float* lp    = (float*)(ws + 589824 + 14680064);
    int*   tcls  = (int*)(ws + 589824 + 14680064 + 262144);

    prep_kernel<<<592, 256, 0, stream>>>(W, scope, label, Wt, tcls);
    logits_kernel<<<512, 256, 0, stream>>>(reps, Wt, b, tcls, probs, lp);
    select_kernel<<<NBAG / 4, 256, 0, stream>>>(scope, lp, probs, out);
}